// Round 3
// baseline (165.608 us; speedup 1.0000x reference)
//
#include <hip/hip_runtime.h>

// affine_grid + grid_sample (bilinear, zeros, align_corners=False)
// N=64, C=3, H=345, W=456, fp32.
constexpr int N_ = 64, C_ = 3, H_ = 345, W_ = 456;
constexpr int HW_ = H_ * W_;

constexpr int TW = 32, TH = 32;                 // output tile (1024 px / block, 4 px/thread)
constexpr int TX = (W_ + TW - 1) / TW;          // 15
constexpr int TY = (H_ + TH - 1) / TH;          // 11
constexpr int TILES = TX * TY;                  // 165
constexpr int RCAP = 48;                        // staged rows capacity
constexpr int CCAP = 68;                        // LDS row stride (272B: 16B-aligned, stride%32=4 banks)
constexpr int CWMAX = 64;                       // max staged cols (16 float4 lanes)

__device__ __forceinline__ float gs_x(int w) {
    const float step  = 2.0f / (float)W_;
    const float start = -(1.0f - 1.0f / (float)W_);
    return (2 * w < W_) ? ((float)w * step + start)
                        : (-start - (float)(W_ - 1 - w) * step);
}
__device__ __forceinline__ float gs_y(int h) {
    const float step  = 2.0f / (float)H_;
    const float start = -(1.0f - 1.0f / (float)H_);
    return (2 * h < H_) ? ((float)h * step + start)
                        : (-start - (float)(H_ - 1 - h) * step);
}

__global__ __launch_bounds__(256) void gs_tiled(
    const float* __restrict__ x,      // [N,3,H,W]
    const float* __restrict__ theta,  // [N,2,3]
    float* __restrict__ out)          // [N,3,H,W]
{
    __shared__ float lds[3][RCAP][CCAP];

    // XCD-affine: batch n -> XCD n%8 only (grid divisible by 8).
    int b    = blockIdx.x;
    int xcd  = b & 7;
    int i    = b >> 3;
    int bg   = i / TILES;
    int tile = i - bg * TILES;
    int n    = xcd + 8 * bg;

    int ty = tile / TX;
    int tx = tile - ty * TX;
    int w0 = tx * TW, h0 = ty * TH;

    const float* t = theta + n * 6;
    float t00 = t[0], t01 = t[1], t02 = t[2];
    float t10 = t[3], t11 = t[4], t12 = t[5];

    const float halfW = 0.5f * (float)W_, cW = 0.5f * (float)(W_ - 1);
    const float halfH = 0.5f * (float)H_, cH = 0.5f * (float)(H_ - 1);

    // ---- source bbox from the 4 tile corners (map affine & monotone in xs,ys) ----
    int we = min(w0 + TW - 1, W_ - 1);
    int he = min(h0 + TH - 1, H_ - 1);
    float xsl = gs_x(w0), xsh = gs_x(we);
    float ysl = gs_y(h0), ysh = gs_y(he);

    float ixa = (xsl * t00 + ysl * t01 + t02) * halfW + cW;
    float ixb = (xsh * t00 + ysl * t01 + t02) * halfW + cW;
    float ixc = (xsl * t00 + ysh * t01 + t02) * halfW + cW;
    float ixd = (xsh * t00 + ysh * t01 + t02) * halfW + cW;
    float iya = (xsl * t10 + ysl * t11 + t12) * halfH + cH;
    float iyb = (xsh * t10 + ysl * t11 + t12) * halfH + cH;
    float iyc = (xsl * t10 + ysh * t11 + t12) * halfH + cH;
    float iyd = (xsh * t10 + ysh * t11 + t12) * halfH + cH;

    float minix = fminf(fminf(ixa, ixb), fminf(ixc, ixd));
    float maxix = fmaxf(fmaxf(ixa, ixb), fmaxf(ixc, ixd));
    float miniy = fminf(fminf(iya, iyb), fminf(iyc, iyd));
    float maxiy = fmaxf(fmaxf(iya, iyb), fmaxf(iyc, iyd));

    // margins: -1/+2 covers bilinear x0+1 and per-op ulp slack
    int x_lo = (int)floorf(minix) - 1, x_hi = (int)floorf(maxix) + 2;
    int y_lo = (int)floorf(miniy) - 1, y_hi = (int)floorf(maxiy) + 2;

    int xa    = x_lo & ~3;                 // align down (works for negatives)
    int cols  = x_hi - xa + 1;
    int cols4 = (cols + 3) >> 2;           // # float4 per row
    int colsp = cols4 << 2;
    int rows  = y_hi - y_lo + 1;

    bool use_lds = (colsp <= CWMAX) && (rows <= RCAP);

    const float* xn = x + (size_t)n * 3 * HW_;
    int tid = threadIdx.x;

    if (use_lds) {
        int j  = tid & 15;                 // float4 column
        int rt = tid >> 4;                 // 16 row-streams
        bool interior = (xa >= 0) && (xa + colsp <= W_) && (y_lo >= 0) && (y_hi < H_);
        if (j < cols4) {
            if (interior) {
                // batch all loads (<=9 float4 in flight), then all LDS writes
                float4 buf[3][3];
                #pragma unroll
                for (int c = 0; c < 3; ++c) {
                    const float* src = xn + c * HW_ + xa + 4 * j;
                    #pragma unroll
                    for (int rr = 0; rr < 3; ++rr) {
                        int r = rt + rr * 16;
                        if (r < rows)
                            buf[c][rr] = *(const float4*)(src + (size_t)(y_lo + r) * W_);
                    }
                }
                #pragma unroll
                for (int c = 0; c < 3; ++c) {
                    #pragma unroll
                    for (int rr = 0; rr < 3; ++rr) {
                        int r = rt + rr * 16;
                        if (r < rows)
                            *(float4*)(&lds[c][r][4 * j]) = buf[c][rr];
                    }
                }
            } else {
                // edge tile: per-element bounds checks, zero-fill
                int xc = xa + 4 * j;
                #pragma unroll
                for (int c = 0; c < 3; ++c) {
                    const float* src = xn + c * HW_;
                    for (int r = rt; r < rows; r += 16) {
                        int y = y_lo + r;
                        bool yok = (unsigned)y < (unsigned)H_;
                        float4 v;
                        v.x = (yok && (unsigned)(xc + 0) < (unsigned)W_) ? src[(size_t)y * W_ + xc + 0] : 0.0f;
                        v.y = (yok && (unsigned)(xc + 1) < (unsigned)W_) ? src[(size_t)y * W_ + xc + 1] : 0.0f;
                        v.z = (yok && (unsigned)(xc + 2) < (unsigned)W_) ? src[(size_t)y * W_ + xc + 2] : 0.0f;
                        v.w = (yok && (unsigned)(xc + 3) < (unsigned)W_) ? src[(size_t)y * W_ + xc + 3] : 0.0f;
                        *(float4*)(&lds[c][r][4 * j]) = v;
                    }
                }
            }
        }
        __syncthreads();                   // block-uniform branch
    }

    // ---- compute: 4 consecutive w-pixels per thread ----
    int twl = (tid & 7) * 4;
    int th  = tid >> 3;
    int w = w0 + twl, h = h0 + th;
    if (w >= W_ || h >= H_) return;        // after the only barrier

    float ys = gs_y(h);
    float acc[3][4];

    #pragma unroll
    for (int p = 0; p < 4; ++p) {
        int wp = w + p;                    // W%4==0 && w<W  =>  wp<W
        float xs = gs_x(wp);
        float ix = (xs * t00 + ys * t01 + t02) * halfW + cW;
        float iy = (xs * t10 + ys * t11 + t12) * halfH + cH;

        float x0f = floorf(ix), y0f = floorf(iy);
        int   X0 = (int)x0f,    Y0 = (int)y0f;
        float fx = ix - x0f,    fy = iy - y0f;
        float gx1 = 1.0f - fx,  gy1 = 1.0f - fy;

        if (use_lds) {
            int lr = Y0 - y_lo, lc = X0 - xa;
            #pragma unroll
            for (int c = 0; c < 3; ++c) {
                float p00 = lds[c][lr][lc],     p10 = lds[c][lr][lc + 1];
                float p01 = lds[c][lr + 1][lc], p11 = lds[c][lr + 1][lc + 1];
                acc[c][p] = (p00 * gx1 + p10 * fx) * gy1 + (p01 * gx1 + p11 * fx) * fy;
            }
        } else {
            float w00 = gx1 * gy1, w10 = fx * gy1, w01 = gx1 * fy, w11 = fx * fy;
            float a0 = 0.0f, a1 = 0.0f, a2 = 0.0f;
#define CORNG(xi, yi, wt)                                                     \
            if ((unsigned)(xi) < (unsigned)W_ && (unsigned)(yi) < (unsigned)H_) { \
                int off = (yi) * W_ + (xi);                                   \
                a0 += xn[off] * (wt);                                         \
                a1 += xn[HW_ + off] * (wt);                                   \
                a2 += xn[2 * HW_ + off] * (wt);                               \
            }
            CORNG(X0,     Y0,     w00)
            CORNG(X0 + 1, Y0,     w10)
            CORNG(X0,     Y0 + 1, w01)
            CORNG(X0 + 1, Y0 + 1, w11)
#undef CORNG
            acc[0][p] = a0; acc[1][p] = a1; acc[2][p] = a2;
        }
    }

    size_t o = (size_t)n * 3 * HW_ + (size_t)h * W_ + w;
    #pragma unroll
    for (int c = 0; c < 3; ++c) {
        float4 v = make_float4(acc[c][0], acc[c][1], acc[c][2], acc[c][3]);
        *(float4*)(out + o + (size_t)c * HW_) = v;
    }
}

extern "C" void kernel_launch(void* const* d_in, const int* in_sizes, int n_in,
                              void* d_out, int out_size, void* d_ws, size_t ws_size,
                              hipStream_t stream) {
    const float* x     = (const float*)d_in[0];
    const float* theta = (const float*)d_in[1];
    float* out = (float*)d_out;

    int blocks = N_ * TILES;   // 10560, divisible by 8
    gs_tiled<<<blocks, 256, 0, stream>>>(x, theta, out);
}

// Round 4
// 58.887 us; speedup vs baseline: 2.8123x; 2.8123x over previous
//
#include <hip/hip_runtime.h>

// affine_grid + grid_sample (bilinear, zeros, align_corners=False)
// N=64, C=3, H=345, W=456, fp32.
constexpr int N_ = 64, C_ = 3, H_ = 345, W_ = 456;
constexpr int HW_ = H_ * W_;

constexpr int TW = 32, TH = 8;                 // output tile, 1 px/thread, 256 threads
constexpr int TX = (W_ + TW - 1) / TW;         // 15
constexpr int TY = (H_ + TH - 1) / TH;         // 44
constexpr int TILES = TX * TY;                 // 660
constexpr int CCAP = 56;                       // staged col capacity & LDS row stride (mult of 4)
constexpr int RCAP = 28;                       // staged row capacity
constexpr int CH_STRIDE = RCAP * CCAP;         // per-channel LDS stride (floats)

__device__ __forceinline__ float gs_x(int w) {
    const float step  = 2.0f / (float)W_;
    const float start = -(1.0f - 1.0f / (float)W_);
    return (2 * w < W_) ? ((float)w * step + start)
                        : (-start - (float)(W_ - 1 - w) * step);
}
__device__ __forceinline__ float gs_y(int h) {
    const float step  = 2.0f / (float)H_;
    const float start = -(1.0f - 1.0f / (float)H_);
    return (2 * h < H_) ? ((float)h * step + start)
                        : (-start - (float)(H_ - 1 - h) * step);
}

__global__ __launch_bounds__(256) void gs_tiled(
    const float* __restrict__ x,      // [N,3,H,W]
    const float* __restrict__ theta,  // [N,2,3]
    float* __restrict__ out)          // [N,3,H,W]
{
    __shared__ float lds[3 * CH_STRIDE];

    // XCD-affine: batch n -> XCD n%8 only (grid divisible by 8).
    int b    = blockIdx.x;
    int xcd  = b & 7;
    int i    = b >> 3;
    int bg   = i / TILES;
    int tile = i - bg * TILES;
    int n    = xcd + 8 * bg;

    int ty = tile / TX;
    int tx = tile - ty * TX;
    int w0 = tx * TW, h0 = ty * TH;

    const float* t = theta + n * 6;
    float t00 = t[0], t01 = t[1], t02 = t[2];
    float t10 = t[3], t11 = t[4], t12 = t[5];

    const float halfW = 0.5f * (float)W_, cW = 0.5f * (float)(W_ - 1);
    const float halfH = 0.5f * (float)H_, cH = 0.5f * (float)(H_ - 1);

    // ---- source bbox from the 4 tile corners (map affine in xs,ys) ----
    int we = min(w0 + TW - 1, W_ - 1);
    int he = min(h0 + TH - 1, H_ - 1);
    float xsl = gs_x(w0), xsh = gs_x(we);
    float ysl = gs_y(h0), ysh = gs_y(he);

    float ixa = (xsl * t00 + ysl * t01 + t02) * halfW + cW;
    float ixb = (xsh * t00 + ysl * t01 + t02) * halfW + cW;
    float ixc = (xsl * t00 + ysh * t01 + t02) * halfW + cW;
    float ixd = (xsh * t00 + ysh * t01 + t02) * halfW + cW;
    float iya = (xsl * t10 + ysl * t11 + t12) * halfH + cH;
    float iyb = (xsh * t10 + ysl * t11 + t12) * halfH + cH;
    float iyc = (xsl * t10 + ysh * t11 + t12) * halfH + cH;
    float iyd = (xsh * t10 + ysh * t11 + t12) * halfH + cH;

    float minix = fminf(fminf(ixa, ixb), fminf(ixc, ixd));
    float maxix = fmaxf(fmaxf(ixa, ixb), fmaxf(ixc, ixd));
    float miniy = fminf(fminf(iya, iyb), fminf(iyc, iyd));
    float maxiy = fmaxf(fmaxf(iya, iyb), fmaxf(iyc, iyd));

    // +-1 margin (fp slack); covers bilinear's +1 corner too
    int x_lo = (int)floorf(minix) - 1, x_hi = (int)floorf(maxix) + 2;
    int y_lo = (int)floorf(miniy) - 1, y_hi = (int)floorf(maxiy) + 2;

    int xa    = x_lo & ~3;                 // align down (ok for negatives)
    int cols  = x_hi - xa + 1;
    int cols4 = (cols + 3) >> 2;
    int colsp = cols4 << 2;
    int rows  = y_hi - y_lo + 1;

    bool use_lds = (colsp <= CCAP) && (rows <= RCAP);

    const float* xn = x + (size_t)n * 3 * HW_;
    int tid = threadIdx.x;

    if (use_lds) {
        int j  = tid & 15;                 // float4 column index
        int rt = tid >> 4;                 // 16 row streams
        if (j < cols4) {
            bool interior = (xa >= 0) && (xa + colsp <= W_) && (y_lo >= 0) && (y_hi < H_);
            if (interior) {
                #pragma unroll
                for (int c = 0; c < 3; ++c) {
                    const float* src = xn + c * HW_ + xa + 4 * j;
                    float* dst = &lds[c * CH_STRIDE + 4 * j];
                    for (int r = rt; r < rows; r += 16)
                        *(float4*)(dst + r * CCAP) = *(const float4*)(src + (size_t)(y_lo + r) * W_);
                }
            } else {
                int xc = xa + 4 * j;
                bool ok0 = (unsigned)(xc + 0) < (unsigned)W_;
                bool ok1 = (unsigned)(xc + 1) < (unsigned)W_;
                bool ok2 = (unsigned)(xc + 2) < (unsigned)W_;
                bool ok3 = (unsigned)(xc + 3) < (unsigned)W_;
                #pragma unroll
                for (int c = 0; c < 3; ++c) {
                    const float* src = xn + c * HW_;
                    float* dst = &lds[c * CH_STRIDE + 4 * j];
                    for (int r = rt; r < rows; r += 16) {
                        int y = y_lo + r;
                        bool yok = (unsigned)y < (unsigned)H_;
                        const float* row = src + (size_t)y * W_ + xc;
                        float4 v;
                        v.x = (yok && ok0) ? row[0] : 0.0f;
                        v.y = (yok && ok1) ? row[1] : 0.0f;
                        v.z = (yok && ok2) ? row[2] : 0.0f;
                        v.w = (yok && ok3) ? row[3] : 0.0f;
                        *(float4*)(dst + r * CCAP) = v;
                    }
                }
            }
        }
        __syncthreads();                   // block-uniform branch: safe
    }

    // ---- compute: 1 px/thread, lanes sweep 32 consecutive w (conflict-free LDS) ----
    int tw = tid & 31, th = tid >> 5;
    int w = w0 + tw, h = h0 + th;
    if (w >= W_ || h >= H_) return;        // after the only barrier

    float xs = gs_x(w), ys = gs_y(h);
    float ix = (xs * t00 + ys * t01 + t02) * halfW + cW;
    float iy = (xs * t10 + ys * t11 + t12) * halfH + cH;

    float x0f = floorf(ix), y0f = floorf(iy);
    float fx = ix - x0f, fy = iy - y0f;

    float a0, a1, a2;
    if (use_lds) {
        int lc = (int)x0f - xa;
        int lr = (int)y0f - y_lo;
        const float* p = &lds[lr * CCAP + lc];
        #pragma unroll
        for (int c = 0; c < 3; ++c) {
            float p00 = p[0], p10 = p[1];
            float p01 = p[CCAP], p11 = p[CCAP + 1];
            float top = fmaf(fx, p10 - p00, p00);
            float bot = fmaf(fx, p11 - p01, p01);
            float v   = fmaf(fy, bot - top, top);
            if (c == 0) a0 = v; else if (c == 1) a1 = v; else a2 = v;
            p += CH_STRIDE;
        }
    } else {
        int X0 = (int)x0f, Y0 = (int)y0f;
        float gx1 = 1.0f - fx, gy1 = 1.0f - fy;
        float w00 = gx1 * gy1, w10 = fx * gy1, w01 = gx1 * fy, w11 = fx * fy;
        a0 = a1 = a2 = 0.0f;
#define CORNG(xi, yi, wt)                                                     \
        if ((unsigned)(xi) < (unsigned)W_ && (unsigned)(yi) < (unsigned)H_) { \
            int off = (yi) * W_ + (xi);                                       \
            a0 += xn[off] * (wt);                                             \
            a1 += xn[HW_ + off] * (wt);                                       \
            a2 += xn[2 * HW_ + off] * (wt);                                   \
        }
        CORNG(X0,     Y0,     w00)
        CORNG(X0 + 1, Y0,     w10)
        CORNG(X0,     Y0 + 1, w01)
        CORNG(X0 + 1, Y0 + 1, w11)
#undef CORNG
    }

    size_t o = (size_t)n * 3 * HW_ + (size_t)h * W_ + w;
    out[o]           = a0;
    out[o + HW_]     = a1;
    out[o + 2 * HW_] = a2;
}

extern "C" void kernel_launch(void* const* d_in, const int* in_sizes, int n_in,
                              void* d_out, int out_size, void* d_ws, size_t ws_size,
                              hipStream_t stream) {
    const float* x     = (const float*)d_in[0];
    const float* theta = (const float*)d_in[1];
    float* out = (float*)d_out;

    int blocks = N_ * TILES;   // 42240, divisible by 8
    gs_tiled<<<blocks, 256, 0, stream>>>(x, theta, out);
}

// Round 5
// 55.126 us; speedup vs baseline: 3.0042x; 1.0682x over previous
//
#include <hip/hip_runtime.h>

// affine_grid + grid_sample (bilinear, zeros, align_corners=False)
// N=64, C=3, H=345, W=456, fp32.
constexpr int N_ = 64, C_ = 3, H_ = 345, W_ = 456;
constexpr int HW_ = H_ * W_;

constexpr int TW = 32, TH = 16;                // output tile: 512 px, 2 px/thread
constexpr int TX = (W_ + TW - 1) / TW;         // 15
constexpr int TY = (H_ + TH - 1) / TH;         // 22
constexpr int TILES = TX * TY;                 // 330
constexpr int CCAP = 56;                       // staged col capacity / LDS row stride
constexpr int RCAP = 39;                       // staged row capacity
constexpr int CH_STRIDE = RCAP * CCAP;         // per-channel LDS stride (floats) = 2184

__global__ __launch_bounds__(256) void gs_tiled(
    const float* __restrict__ x,      // [N,3,H,W]
    const float* __restrict__ theta,  // [N,2,3]
    float* __restrict__ out)          // [N,3,H,W]
{
    __shared__ float lds[3 * CH_STRIDE];

    // XCD-affine: batch n -> XCD n%8 only (grid divisible by 8).
    int b    = blockIdx.x;
    int xcd  = b & 7;
    int i    = b >> 3;
    int bg   = i / TILES;
    int tile = i - bg * TILES;
    int n    = xcd + 8 * bg;

    int ty = tile / TX;
    int tx = tile - ty * TX;
    int w0 = tx * TW, h0 = ty * TH;

    const float* t = theta + n * 6;
    float t00 = t[0], t01 = t[1], t02 = t[2];
    float t10 = t[3], t11 = t[4], t12 = t[5];

    const float halfW = 0.5f * (float)W_, cW = 0.5f * (float)(W_ - 1);
    const float halfH = 0.5f * (float)H_, cH = 0.5f * (float)(H_ - 1);
    const float startx = -(1.0f - 1.0f / (float)W_);
    const float starty = -(1.0f - 1.0f / (float)H_);

    // Linear map: ix = Ax*w + Bx*h + Cx ; iy = Ay*w + By*h + Cy
    float Ax = t00;
    float Bx = t01 * ((float)W_ / (float)H_);
    float Cx = fmaf(startx, t00, fmaf(starty, t01, t02)) * halfW + cW;
    float Ay = t10 * ((float)H_ / (float)W_);
    float By = t11;
    float Cy = fmaf(startx, t10, fmaf(starty, t11, t12)) * halfH + cH;

    // ---- source bbox over the (clamped) tile, exact for the linear map ----
    float ws = (float)w0, we = (float)min(w0 + TW - 1, W_ - 1);
    float hs = (float)h0, he = (float)min(h0 + TH - 1, H_ - 1);

    float xw0 = ws * Ax, xw1 = we * Ax;
    float xh0 = hs * Bx, xh1 = he * Bx;
    float minix = Cx + fminf(xw0, xw1) + fminf(xh0, xh1);
    float maxix = Cx + fmaxf(xw0, xw1) + fmaxf(xh0, xh1);

    float yw0 = ws * Ay, yw1 = we * Ay;
    float yh0 = hs * By, yh1 = he * By;
    float miniy = Cy + fminf(yw0, yw1) + fminf(yh0, yh1);
    float maxiy = Cy + fmaxf(yw0, yw1) + fmaxf(yh0, yh1);

    // +-1 margin (fp slack); +1 more on hi for bilinear's +1 corner
    int x_lo = (int)floorf(minix) - 1, x_hi = (int)floorf(maxix) + 2;
    int y_lo = (int)floorf(miniy) - 1, y_hi = (int)floorf(maxiy) + 2;

    int xa    = x_lo & ~3;                 // align down (ok for negatives)
    int cols  = x_hi - xa + 1;
    int cols4 = (cols + 3) >> 2;
    int colsp = cols4 << 2;
    int rows  = y_hi - y_lo + 1;

    bool use_lds = (colsp <= CCAP) && (rows <= RCAP);

    const float* xn = x + (size_t)n * 3 * HW_;
    int tid = threadIdx.x;

    if (use_lds) {
        int j  = tid & 15;                 // float4 column index
        int rt = tid >> 4;                 // 16 row streams
        if (j < cols4) {
            bool interior = (xa >= 0) && (xa + colsp <= W_) && (y_lo >= 0) && (y_hi < H_);
            if (interior) {
                #pragma unroll
                for (int c = 0; c < 3; ++c) {
                    const float* src = xn + c * HW_ + xa + 4 * j;
                    float* dst = &lds[c * CH_STRIDE + 4 * j];
                    for (int r = rt; r < rows; r += 16)
                        *(float4*)(dst + r * CCAP) = *(const float4*)(src + (size_t)(y_lo + r) * W_);
                }
            } else {
                int xc = xa + 4 * j;
                bool ok0 = (unsigned)(xc + 0) < (unsigned)W_;
                bool ok1 = (unsigned)(xc + 1) < (unsigned)W_;
                bool ok2 = (unsigned)(xc + 2) < (unsigned)W_;
                bool ok3 = (unsigned)(xc + 3) < (unsigned)W_;
                #pragma unroll
                for (int c = 0; c < 3; ++c) {
                    const float* src = xn + c * HW_;
                    float* dst = &lds[c * CH_STRIDE + 4 * j];
                    for (int r = rt; r < rows; r += 16) {
                        int y = y_lo + r;
                        bool yok = (unsigned)y < (unsigned)H_;
                        const float* row = src + (size_t)y * W_ + xc;
                        float4 v;
                        v.x = (yok && ok0) ? row[0] : 0.0f;
                        v.y = (yok && ok1) ? row[1] : 0.0f;
                        v.z = (yok && ok2) ? row[2] : 0.0f;
                        v.w = (yok && ok3) ? row[3] : 0.0f;
                        *(float4*)(dst + r * CCAP) = v;
                    }
                }
            }
        }
        __syncthreads();                   // block-uniform branch: safe
    }

    // ---- compute: 2 consecutive-w px/thread ----
    int tw = (tid & 15) * 2, th = tid >> 4;
    int w = w0 + tw, h = h0 + th;
    if (w >= W_ || h >= H_) return;        // after the only barrier; pair fully in (W even)

    float fw = (float)w, fh = (float)h;
    float hx  = fmaf(fh, Bx, Cx), hy = fmaf(fh, By, Cy);
    float ixA = fmaf(fw, Ax, hx), iyA = fmaf(fw, Ay, hy);
    float ixB = ixA + Ax,         iyB = iyA + Ay;

    float xfA = floorf(ixA), yfA = floorf(iyA);
    float fxA = ixA - xfA,   fyA = iyA - yfA;
    int   XA  = (int)xfA,    YA  = (int)yfA;

    float xfB = floorf(ixB), yfB = floorf(iyB);
    float fxB = ixB - xfB,   fyB = iyB - yfB;
    int   XB  = (int)xfB,    YB  = (int)yfB;

    float vA0, vA1, vA2, vB0, vB1, vB2;

    if (use_lds) {
        const float* pA = &lds[(YA - y_lo) * CCAP + (XA - xa)];
        const float* pB = &lds[(YB - y_lo) * CCAP + (XB - xa)];

        // channel 0
        {
            float a00 = pA[0], a10 = pA[1], a01 = pA[CCAP], a11 = pA[CCAP + 1];
            float b00 = pB[0], b10 = pB[1], b01 = pB[CCAP], b11 = pB[CCAP + 1];
            float at = fmaf(fxA, a10 - a00, a00), ab = fmaf(fxA, a11 - a01, a01);
            float bt = fmaf(fxB, b10 - b00, b00), bb = fmaf(fxB, b11 - b01, b01);
            vA0 = fmaf(fyA, ab - at, at);
            vB0 = fmaf(fyB, bb - bt, bt);
        }
        // channel 1
        {
            float a00 = pA[CH_STRIDE], a10 = pA[CH_STRIDE + 1];
            float a01 = pA[CH_STRIDE + CCAP], a11 = pA[CH_STRIDE + CCAP + 1];
            float b00 = pB[CH_STRIDE], b10 = pB[CH_STRIDE + 1];
            float b01 = pB[CH_STRIDE + CCAP], b11 = pB[CH_STRIDE + CCAP + 1];
            float at = fmaf(fxA, a10 - a00, a00), ab = fmaf(fxA, a11 - a01, a01);
            float bt = fmaf(fxB, b10 - b00, b00), bb = fmaf(fxB, b11 - b01, b01);
            vA1 = fmaf(fyA, ab - at, at);
            vB1 = fmaf(fyB, bb - bt, bt);
        }
        // channel 2
        {
            float a00 = pA[2 * CH_STRIDE], a10 = pA[2 * CH_STRIDE + 1];
            float a01 = pA[2 * CH_STRIDE + CCAP], a11 = pA[2 * CH_STRIDE + CCAP + 1];
            float b00 = pB[2 * CH_STRIDE], b10 = pB[2 * CH_STRIDE + 1];
            float b01 = pB[2 * CH_STRIDE + CCAP], b11 = pB[2 * CH_STRIDE + CCAP + 1];
            float at = fmaf(fxA, a10 - a00, a00), ab = fmaf(fxA, a11 - a01, a01);
            float bt = fmaf(fxB, b10 - b00, b00), bb = fmaf(fxB, b11 - b01, b01);
            vA2 = fmaf(fyA, ab - at, at);
            vB2 = fmaf(fyB, bb - bt, bt);
        }
    } else {
        float gxA = 1.0f - fxA, gyA = 1.0f - fyA;
        float gxB = 1.0f - fxB, gyB = 1.0f - fyB;
        float wA00 = gxA * gyA, wA10 = fxA * gyA, wA01 = gxA * fyA, wA11 = fxA * fyA;
        float wB00 = gxB * gyB, wB10 = fxB * gyB, wB01 = gxB * fyB, wB11 = fxB * fyB;
        vA0 = vA1 = vA2 = vB0 = vB1 = vB2 = 0.0f;
#define CORNG(xi, yi, wt, d0, d1, d2)                                         \
        if ((unsigned)(xi) < (unsigned)W_ && (unsigned)(yi) < (unsigned)H_) { \
            int off = (yi) * W_ + (xi);                                       \
            d0 += xn[off] * (wt);                                             \
            d1 += xn[HW_ + off] * (wt);                                       \
            d2 += xn[2 * HW_ + off] * (wt);                                   \
        }
        CORNG(XA,     YA,     wA00, vA0, vA1, vA2)
        CORNG(XA + 1, YA,     wA10, vA0, vA1, vA2)
        CORNG(XA,     YA + 1, wA01, vA0, vA1, vA2)
        CORNG(XA + 1, YA + 1, wA11, vA0, vA1, vA2)
        CORNG(XB,     YB,     wB00, vB0, vB1, vB2)
        CORNG(XB + 1, YB,     wB10, vB0, vB1, vB2)
        CORNG(XB,     YB + 1, wB01, vB0, vB1, vB2)
        CORNG(XB + 1, YB + 1, wB11, vB0, vB1, vB2)
#undef CORNG
    }

    size_t o = (size_t)n * 3 * HW_ + (size_t)h * W_ + w;
    *(float2*)(out + o)           = make_float2(vA0, vB0);
    *(float2*)(out + o + HW_)     = make_float2(vA1, vB1);
    *(float2*)(out + o + 2 * HW_) = make_float2(vA2, vB2);
}

extern "C" void kernel_launch(void* const* d_in, const int* in_sizes, int n_in,
                              void* d_out, int out_size, void* d_ws, size_t ws_size,
                              hipStream_t stream) {
    const float* x     = (const float*)d_in[0];
    const float* theta = (const float*)d_in[1];
    float* out = (float*)d_out;

    int blocks = N_ * TILES;   // 21120, divisible by 8
    gs_tiled<<<blocks, 256, 0, stream>>>(x, theta, out);
}

// Round 6
// 46.719 us; speedup vs baseline: 3.5448x; 1.1800x over previous
//
#include <hip/hip_runtime.h>

// affine_grid + grid_sample (bilinear, zeros, align_corners=False)
// N=64, C=3, H=345, W=456, fp32.
constexpr int N_ = 64, C_ = 3, H_ = 345, W_ = 456;
constexpr int HW_ = H_ * W_;

constexpr int TW = 32, TH = 16;                // output tile: 512 px, 2 px/thread
constexpr int TX = (W_ + TW - 1) / TW;         // 15
constexpr int TY = (H_ + TH - 1) / TH;         // 22
constexpr int TILES = TX * TY;                 // 330
constexpr int CCAP = 52;                       // staged col capacity / LDS row stride (x4B=208B, 13 float4)
constexpr int RCAP = 28;                       // staged row capacity
constexpr int CJ   = CCAP / 4;                 // 13 float4 columns
constexpr int CH_STRIDE = RCAP * CCAP;         // per-channel LDS floats = 1456 (17472 B total)

__global__ __launch_bounds__(256, 8) void gs_tiled(
    const float* __restrict__ x,      // [N,3,H,W]
    const float* __restrict__ theta,  // [N,2,3]
    float* __restrict__ out)          // [N,3,H,W]
{
    __shared__ float lds[3 * CH_STRIDE];

    // XCD-affine: batch n -> XCD n%8 only (grid divisible by 8).
    int b    = blockIdx.x;
    int xcd  = b & 7;
    int i    = b >> 3;
    int bg   = i / TILES;
    int tile = i - bg * TILES;
    int n    = xcd + 8 * bg;

    int ty = tile / TX;
    int tx = tile - ty * TX;
    int w0 = tx * TW, h0 = ty * TH;

    const float* t = theta + n * 6;
    float t00 = t[0], t01 = t[1], t02 = t[2];
    float t10 = t[3], t11 = t[4], t12 = t[5];

    const float halfW = 0.5f * (float)W_, cW = 0.5f * (float)(W_ - 1);
    const float halfH = 0.5f * (float)H_, cH = 0.5f * (float)(H_ - 1);
    const float startx = -(1.0f - 1.0f / (float)W_);
    const float starty = -(1.0f - 1.0f / (float)H_);

    // Linear map: ix = Ax*w + Bx*h + Cx ; iy = Ay*w + By*h + Cy
    float Ax = t00;
    float Bx = t01 * ((float)W_ / (float)H_);
    float Cx = fmaf(startx, t00, fmaf(starty, t01, t02)) * halfW + cW;
    float Ay = t10 * ((float)H_ / (float)W_);
    float By = t11;
    float Cy = fmaf(startx, t10, fmaf(starty, t11, t12)) * halfH + cH;

    // ---- source bbox over the (clamped) tile, exact for the linear map ----
    float ws = (float)w0, we = (float)min(w0 + TW - 1, W_ - 1);
    float hs = (float)h0, he = (float)min(h0 + TH - 1, H_ - 1);

    float xw0 = ws * Ax, xw1 = we * Ax;
    float xh0 = hs * Bx, xh1 = he * Bx;
    float minix = Cx + fminf(xw0, xw1) + fminf(xh0, xh1);
    float maxix = Cx + fmaxf(xw0, xw1) + fmaxf(xh0, xh1);

    float yw0 = ws * Ay, yw1 = we * Ay;
    float yh0 = hs * By, yh1 = he * By;
    float miniy = Cy + fminf(yw0, yw1) + fminf(yh0, yh1);
    float maxiy = Cy + fmaxf(yw0, yw1) + fmaxf(yh0, yh1);

    // +-1 margin (fp slack); +1 more on hi for bilinear's +1 corner
    int x_lo = (int)floorf(minix) - 1, x_hi = (int)floorf(maxix) + 2;
    int y_lo = (int)floorf(miniy) - 1, y_hi = (int)floorf(maxiy) + 2;

    int xa    = x_lo & ~3;                 // align down (ok for negatives)
    int cols  = x_hi - xa + 1;
    int cols4 = (cols + 3) >> 2;
    if (cols4 > CJ) {                      // capacity overflow: center the window
        xa += ((cols4 - CJ) >> 1) << 2;
        cols4 = CJ;
    }
    int colsp = cols4 << 2;
    int rows  = y_hi - y_lo + 1;
    if (rows > RCAP) {
        y_lo += (rows - RCAP) >> 1;
        rows = RCAP;
    }

    const float* xn = x + (size_t)n * 3 * HW_;
    int tid = threadIdx.x;

    // ---- stage window [xa, xa+colsp) x [y_lo, y_lo+rows) zero-filled ----
    {
        int j  = tid & 15;                 // float4 column index (16 lanes, CJ=13 active)
        int rt = tid >> 4;                 // 16 row streams
        if (j < cols4) {
            bool interior = (xa >= 0) && (xa + colsp <= W_) && (y_lo >= 0) && (y_lo + rows <= H_);
            if (interior) {
                #pragma unroll
                for (int c = 0; c < 3; ++c) {
                    const float* src = xn + c * HW_ + xa + 4 * j;
                    float* dst = &lds[c * CH_STRIDE + 4 * j];
                    for (int r = rt; r < rows; r += 16)
                        *(float4*)(dst + r * CCAP) = *(const float4*)(src + (size_t)(y_lo + r) * W_);
                }
            } else {
                int xc = xa + 4 * j;
                bool ok0 = (unsigned)(xc + 0) < (unsigned)W_;
                bool ok1 = (unsigned)(xc + 1) < (unsigned)W_;
                bool ok2 = (unsigned)(xc + 2) < (unsigned)W_;
                bool ok3 = (unsigned)(xc + 3) < (unsigned)W_;
                #pragma unroll
                for (int c = 0; c < 3; ++c) {
                    const float* src = xn + c * HW_;
                    float* dst = &lds[c * CH_STRIDE + 4 * j];
                    for (int r = rt; r < rows; r += 16) {
                        int y = y_lo + r;
                        bool yok = (unsigned)y < (unsigned)H_;
                        const float* row = src + (size_t)y * W_ + xc;
                        float4 v;
                        v.x = (yok && ok0) ? row[0] : 0.0f;
                        v.y = (yok && ok1) ? row[1] : 0.0f;
                        v.z = (yok && ok2) ? row[2] : 0.0f;
                        v.w = (yok && ok3) ? row[3] : 0.0f;
                        *(float4*)(dst + r * CCAP) = v;
                    }
                }
            }
        }
        __syncthreads();
    }

    // ---- compute: 2 consecutive-w px/thread ----
    int tw = (tid & 15) * 2, th = tid >> 4;
    int w = w0 + tw, h = h0 + th;
    if (w >= W_ || h >= H_) return;        // after the only barrier; pair fully in (W even)

    float fw = (float)w, fh = (float)h;
    float hx  = fmaf(fh, Bx, Cx), hy = fmaf(fh, By, Cy);
    float ixA = fmaf(fw, Ax, hx), iyA = fmaf(fw, Ay, hy);
    float ixB = ixA + Ax,         iyB = iyA + Ay;

    float xfA = floorf(ixA), yfA = floorf(iyA);
    float fxA = ixA - xfA,   fyA = iyA - yfA;
    int   XA  = (int)xfA,    YA  = (int)yfA;

    float xfB = floorf(ixB), yfB = floorf(iyB);
    float fxB = ixB - xfB,   fyB = iyB - yfB;
    int   XB  = (int)xfB,    YB  = (int)yfB;

    int lcA = XA - xa, lrA = YA - y_lo;
    int lcB = XB - xa, lrB = YB - y_lo;
    bool inA = (unsigned)lcA < (unsigned)(colsp - 1) && (unsigned)lrA < (unsigned)(rows - 1);
    bool inB = (unsigned)lcB < (unsigned)(colsp - 1) && (unsigned)lrB < (unsigned)(rows - 1);

    float vA0, vA1, vA2, vB0, vB1, vB2;

    if (__builtin_expect(inA & inB, 1)) {
        const float* pA = &lds[lrA * CCAP + lcA];
        const float* pB = &lds[lrB * CCAP + lcB];
        // channel 0
        {
            float a00 = pA[0], a10 = pA[1], a01 = pA[CCAP], a11 = pA[CCAP + 1];
            float b00 = pB[0], b10 = pB[1], b01 = pB[CCAP], b11 = pB[CCAP + 1];
            float at = fmaf(fxA, a10 - a00, a00), ab = fmaf(fxA, a11 - a01, a01);
            float bt = fmaf(fxB, b10 - b00, b00), bb = fmaf(fxB, b11 - b01, b01);
            vA0 = fmaf(fyA, ab - at, at);
            vB0 = fmaf(fyB, bb - bt, bt);
        }
        // channel 1
        {
            float a00 = pA[CH_STRIDE], a10 = pA[CH_STRIDE + 1];
            float a01 = pA[CH_STRIDE + CCAP], a11 = pA[CH_STRIDE + CCAP + 1];
            float b00 = pB[CH_STRIDE], b10 = pB[CH_STRIDE + 1];
            float b01 = pB[CH_STRIDE + CCAP], b11 = pB[CH_STRIDE + CCAP + 1];
            float at = fmaf(fxA, a10 - a00, a00), ab = fmaf(fxA, a11 - a01, a01);
            float bt = fmaf(fxB, b10 - b00, b00), bb = fmaf(fxB, b11 - b01, b01);
            vA1 = fmaf(fyA, ab - at, at);
            vB1 = fmaf(fyB, bb - bt, bt);
        }
        // channel 2
        {
            float a00 = pA[2 * CH_STRIDE], a10 = pA[2 * CH_STRIDE + 1];
            float a01 = pA[2 * CH_STRIDE + CCAP], a11 = pA[2 * CH_STRIDE + CCAP + 1];
            float b00 = pB[2 * CH_STRIDE], b10 = pB[2 * CH_STRIDE + 1];
            float b01 = pB[2 * CH_STRIDE + CCAP], b11 = pB[2 * CH_STRIDE + CCAP + 1];
            float at = fmaf(fxA, a10 - a00, a00), ab = fmaf(fxA, a11 - a01, a01);
            float bt = fmaf(fxB, b10 - b00, b00), bb = fmaf(fxB, b11 - b01, b01);
            vA2 = fmaf(fyA, ab - at, at);
            vB2 = fmaf(fyB, bb - bt, bt);
        }
    } else {
        // rare: corner(s) outside staged window -> direct global gather (zeros pad)
        float gxA = 1.0f - fxA, gyA = 1.0f - fyA;
        float gxB = 1.0f - fxB, gyB = 1.0f - fyB;
        float wA00 = gxA * gyA, wA10 = fxA * gyA, wA01 = gxA * fyA, wA11 = fxA * fyA;
        float wB00 = gxB * gyB, wB10 = fxB * gyB, wB01 = gxB * fyB, wB11 = fxB * fyB;
        vA0 = vA1 = vA2 = vB0 = vB1 = vB2 = 0.0f;
#define CORNG(xi, yi, wt, d0, d1, d2)                                         \
        if ((unsigned)(xi) < (unsigned)W_ && (unsigned)(yi) < (unsigned)H_) { \
            int off = (yi) * W_ + (xi);                                       \
            d0 += xn[off] * (wt);                                             \
            d1 += xn[HW_ + off] * (wt);                                       \
            d2 += xn[2 * HW_ + off] * (wt);                                   \
        }
        CORNG(XA,     YA,     wA00, vA0, vA1, vA2)
        CORNG(XA + 1, YA,     wA10, vA0, vA1, vA2)
        CORNG(XA,     YA + 1, wA01, vA0, vA1, vA2)
        CORNG(XA + 1, YA + 1, wA11, vA0, vA1, vA2)
        CORNG(XB,     YB,     wB00, vB0, vB1, vB2)
        CORNG(XB + 1, YB,     wB10, vB0, vB1, vB2)
        CORNG(XB,     YB + 1, wB01, vB0, vB1, vB2)
        CORNG(XB + 1, YB + 1, wB11, vB0, vB1, vB2)
#undef CORNG
    }

    size_t o = (size_t)n * 3 * HW_ + (size_t)h * W_ + w;
    *(float2*)(out + o)           = make_float2(vA0, vB0);
    *(float2*)(out + o + HW_)     = make_float2(vA1, vB1);
    *(float2*)(out + o + 2 * HW_) = make_float2(vA2, vB2);
}

extern "C" void kernel_launch(void* const* d_in, const int* in_sizes, int n_in,
                              void* d_out, int out_size, void* d_ws, size_t ws_size,
                              hipStream_t stream) {
    const float* x     = (const float*)d_in[0];
    const float* theta = (const float*)d_in[1];
    float* out = (float*)d_out;

    int blocks = N_ * TILES;   // 21120, divisible by 8
    gs_tiled<<<blocks, 256, 0, stream>>>(x, theta, out);
}